// Round 10
// baseline (62.037 us; speedup 1.0000x reference)
//
#include <hip/hip_runtime.h>
#include <hip/hip_bf16.h>
#include <stdint.h>

#define NROWS 8192
#define DDIM  128
#define NBLK  64                        // 8192 / 128
#define NPAIR (NBLK * (NBLK + 1) / 2)   // 2080 upper-triangle tile pairs
#define BI 128
#define BJ 128
#define PANEL_BYTES (BJ * DDIM)         // fp8: 16384 B

typedef __attribute__((ext_vector_type(4))) float f32x4;
typedef long f8x8;           // 8 fp8 elements = 8 bytes = 2 VGPRs

__device__ __forceinline__ void load_lds16(const void* g, void* l) {
    __builtin_amdgcn_global_load_lds(
        (const __attribute__((address_space(1))) void*)g,
        (__attribute__((address_space(3))) void*)l, 16, 0, 0);
}

// (1/tau) * log2(e); q is pre-scaled by sqrt of this so exp2(acc) = e^{s/tau}.
#define SCALE 14.426950408889634f
#define E10   22026.465794806718f   // exp(1/tau) exact diagonal term

// ---------- Kernel 1: row-normalize fp32 -> scaled fp8, emit ||q||^2 -----
__global__ __launch_bounds__(256) void normalize_kernel(
    const float* __restrict__ x, unsigned short* __restrict__ q16,
    float* __restrict__ dsq)
{
    int wave = threadIdx.x >> 6;
    int lane = threadIdx.x & 63;
    int row  = blockIdx.x * 4 + wave;
    const float2* xr = (const float2*)(x + (size_t)row * DDIM);
    float2 v = xr[lane];
    float ss = v.x * v.x + v.y * v.y;
    #pragma unroll
    for (int off = 1; off < 64; off <<= 1)
        ss += __shfl_xor(ss, off, 64);
    float rn = sqrtf(SCALE / ss);
    int pk = __builtin_amdgcn_cvt_pk_fp8_f32(v.x * rn, v.y * rn, 0, false);
    q16[(size_t)row * 64 + lane] = (unsigned short)(pk & 0xffff);
    // exact quantized self-energy (matches what the MFMA diagonal computes)
    float d0 = __builtin_amdgcn_cvt_f32_fp8(pk, 0);
    float d1 = __builtin_amdgcn_cvt_f32_fp8(pk, 1);
    float sq = d0 * d0 + d1 * d1;
    #pragma unroll
    for (int off = 1; off < 64; off <<= 1)
        sq += __shfl_xor(sq, off, 64);
    if (lane == 0) dsq[row] = sq;
}

// ---------- Kernel 2: SYMMETRIC fused fp8 QQ^T + exp2 + masked sums ------
// S is symmetric: compute only tile-pairs (ib <= jb), 2080 blocks of
// 128 rows x 128 cols. Each e_ij is credited to row i (row-sum, in-reg)
// AND row j (col-sum, nearly free from the MFMA layout: each lane's 4 acc
// elements share one column). Unique-writer slot scheme (no atomics):
// block (ib,jb): row-side -> slot jb (rows ib*128..), col-side -> slot ib
// (rows jb*128..); diagonal blocks skip col-side. Every (slot, rowblock)
// has exactly one writer -> deterministic, no zero-init needed.
// R6-proven staging: whole j-panel once (16 KB), pre-swizzled source
// (involution on byte bits 4-6 keyed by col&7), one barrier, then a
// barrier-free hot loop with NO inline asm.
__global__ __launch_bounds__(256, 4) void sim_kernel(
    const unsigned short* __restrict__ q16, const int* __restrict__ y,
    float* __restrict__ topp, float* __restrict__ downp)
{
    __shared__ char  smem[PANEL_BYTES];
    __shared__ int   yl[BJ];
    __shared__ float scolD[4][BJ];
    __shared__ float scolT[4][BJ];

    // decode upper-triangle pair: 0 <= ib <= jb < 64
    int k = blockIdx.x;
    int jb = (int)((sqrtf(8.0f * (float)k + 1.0f) - 1.0f) * 0.5f);
    while ((jb + 1) * (jb + 2) / 2 <= k) ++jb;
    while (jb * (jb + 1) / 2 > k) --jb;
    int ib = k - jb * (jb + 1) / 2;

    const int tid  = threadIdx.x;
    const int lane = tid & 63;
    const int wave = tid >> 6;
    const int lrow = lane & 15;
    const int lhi  = lane >> 4;

    const char* qb = (const char*)q16;
    const int rbase = ib * BI + wave * 32;
    const int jbase = jb * BJ;

    if (tid < BJ) yl[tid] = y[jbase + tid];

    // stage the whole j-panel: linear LDS dest, pre-swizzled source
    #pragma unroll
    for (int p = 0; p < 4; ++p) {
        int phys = p * 4096 + tid * 16;
        int col  = phys >> 7;
        int L    = phys ^ ((col & 7) << 4);
        load_lds16(qb + (size_t)(jbase + col) * DDIM + (L & 127), smem + phys);
    }

    // A fragments: 2 row-tiles x 4 K-slices, 8B each (16 VGPRs total).
    f8x8 afrag[2][4];
    #pragma unroll
    for (int t = 0; t < 2; ++t)
        #pragma unroll
        for (int ks = 0; ks < 4; ++ks)
            afrag[t][ks] = *(const f8x8*)(qb +
                (size_t)(rbase + t * 16 + lrow) * DDIM + ks * 32 + lhi * 8);

    int yrow[2][4];
    #pragma unroll
    for (int t = 0; t < 2; ++t)
        #pragma unroll
        for (int r = 0; r < 4; ++r)
            yrow[t][r] = y[rbase + t * 16 + lhi * 4 + r];

    __syncthreads();   // panel + labels staged; hot loop is barrier-free

    float top[2][4]  = {};
    float down[2][4] = {};
    float colD[8] = {};
    float colT[8] = {};

    #pragma unroll
    for (int jt = 0; jt < 8; ++jt) {
        const int cg = jt * 16 + lrow;
        const int ycol = yl[cg];
        f8x8 bfrag[4];
        #pragma unroll
        for (int ks = 0; ks < 4; ++ks) {
            int off = cg * DDIM + ((ks * 32 + lhi * 8) ^ ((cg & 7) << 4));
            bfrag[ks] = *(const f8x8*)(smem + off);
        }
        #pragma unroll
        for (int t = 0; t < 2; ++t) {
            f32x4 acc = {0.f, 0.f, 0.f, 0.f};
            #pragma unroll
            for (int ks = 0; ks < 4; ++ks)
                acc = __builtin_amdgcn_mfma_f32_16x16x32_fp8_fp8(
                    afrag[t][ks], bfrag[ks], acc, 0, 0, 0);
            #pragma unroll
            for (int r = 0; r < 4; ++r) {
                float e  = __builtin_amdgcn_exp2f(acc[r]);
                float me = (yrow[t][r] == ycol) ? e : 0.0f;
                down[t][r] += e;
                top[t][r]  += me;
                colD[jt] += e;     // this lane's column partial (4 rows/t)
                colT[jt] += me;
            }
        }
    }

    // ---- row-side: reduce across the 16 column-lanes ----
    #pragma unroll
    for (int m = 1; m < 16; m <<= 1) {
        #pragma unroll
        for (int t = 0; t < 2; ++t)
            #pragma unroll
            for (int r = 0; r < 4; ++r) {
                top[t][r]  += __shfl_xor(top[t][r],  m, 64);
                down[t][r] += __shfl_xor(down[t][r], m, 64);
            }
    }
    if (lrow == 0) {
        #pragma unroll
        for (int t = 0; t < 2; ++t)
            #pragma unroll
            for (int r = 0; r < 4; ++r) {
                int row = rbase + t * 16 + lhi * 4 + r;
                topp [jb * NROWS + row] = top[t][r];
                downp[jb * NROWS + row] = down[t][r];
            }
    }

    // ---- col-side: reduce over the 4 lhi groups, then across waves ----
    #pragma unroll
    for (int jt = 0; jt < 8; ++jt) {
        colD[jt] += __shfl_xor(colD[jt], 16, 64);
        colD[jt] += __shfl_xor(colD[jt], 32, 64);
        colT[jt] += __shfl_xor(colT[jt], 16, 64);
        colT[jt] += __shfl_xor(colT[jt], 32, 64);
    }
    if (lane < 16) {
        #pragma unroll
        for (int jt = 0; jt < 8; ++jt) {
            scolD[wave][jt * 16 + lane] = colD[jt];
            scolT[wave][jt * 16 + lane] = colT[jt];
        }
    }
    __syncthreads();
    if (ib != jb && tid < BJ) {
        float cd = scolD[0][tid] + scolD[1][tid] + scolD[2][tid] + scolD[3][tid];
        float ct = scolT[0][tid] + scolT[1][tid] + scolT[2][tid] + scolT[3][tid];
        downp[ib * NROWS + jbase + tid] = cd;
        topp [ib * NROWS + jbase + tid] = ct;
    }
}

// ---------- Kernel 3a: per-row loss with exact-diagonal correction -------
__global__ __launch_bounds__(64) void loss_partial_kernel(
    const float* __restrict__ topp, const float* __restrict__ downp,
    const float* __restrict__ dsq, float* __restrict__ partial)
{
    const int lane = threadIdx.x;
    const int r = blockIdx.x * 64 + lane;
    float t = 0.f, d = 0.f;
    #pragma unroll 8
    for (int hh = 0; hh < NBLK; ++hh) {
        t += topp [hh * NROWS + r];
        d += downp[hh * NROWS + r];
    }
    // replace quantized diagonal exp2(||q||^2) with exact e^{1/tau}
    float e2d = __builtin_amdgcn_exp2f(dsq[r]);
    t = t - e2d + E10;
    d = d - e2d + E10;
    float s = __logf(d) - __logf(t);
    #pragma unroll
    for (int off = 1; off < 64; off <<= 1)
        s += __shfl_xor(s, off, 64);
    if (lane == 0) partial[blockIdx.x] = s;
}

// ---------- Kernel 3b: final 128 -> scalar -------------------------------
__global__ __launch_bounds__(64) void loss_final_kernel(
    const float* __restrict__ partial, float* __restrict__ out)
{
    const int lane = threadIdx.x;
    float s = partial[lane] + partial[lane + 64];
    #pragma unroll
    for (int off = 1; off < 64; off <<= 1)
        s += __shfl_xor(s, off, 64);
    if (lane == 0) out[0] = s / (float)NROWS;
}

extern "C" void kernel_launch(void* const* d_in, const int* in_sizes, int n_in,
                              void* d_out, int out_size, void* d_ws, size_t ws_size,
                              hipStream_t stream)
{
    const float* x = (const float*)d_in[0];
    const int*   y = (const int*)d_in[1];
    float* out = (float*)d_out;

    char* ws = (char*)d_ws;
    unsigned short* q16 = (unsigned short*)ws;                     // 1 MB fp8
    float* topp  = (float*)(ws + (size_t)NROWS * DDIM);            // 2 MB
    float* downp = topp + NBLK * NROWS;                            // 2 MB
    float* dsq     = downp + NBLK * NROWS;                         // 32 KB
    float* partial = dsq + NROWS;                                  // 512 B

    normalize_kernel<<<NROWS / 4, 256, 0, stream>>>(x, q16, dsq);
    sim_kernel<<<NPAIR, 256, 0, stream>>>(q16, y, topp, downp);
    loss_partial_kernel<<<NROWS / 64, 64, 0, stream>>>(topp, downp, dsq, partial);
    loss_final_kernel<<<1, 64, 0, stream>>>(partial, out);
}

// Round 11
// 52.171 us; speedup vs baseline: 1.1891x; 1.1891x over previous
//
#include <hip/hip_runtime.h>
#include <hip/hip_bf16.h>
#include <stdint.h>

#define NROWS 8192
#define DDIM  128
#define NCHUNK 16            // column chunks (partial-sum slots)
#define ROWS_PER_BLOCK 128   // 4 waves x 32 rows
#define COLS_PER_BLOCK 512   // NROWS / NCHUNK
#define GROUP_COLS 64        // cols staged per LDS buffer
#define GROUP_BYTES (GROUP_COLS * DDIM)       // fp8: 8192 B
#define NGROUPS (COLS_PER_BLOCK / GROUP_COLS) // 8

typedef __attribute__((ext_vector_type(4))) float f32x4;
typedef long f8x8;           // 8 fp8 elements = 8 bytes = 2 VGPRs

__device__ __forceinline__ void load_lds16(const void* g, void* l) {
    __builtin_amdgcn_global_load_lds(
        (const __attribute__((address_space(1))) void*)g,
        (__attribute__((address_space(3))) void*)l, 16, 0, 0);
}

// (1/tau) * log2(e); q is pre-scaled by sqrt of this so exp2(acc) = e^{s/tau}.
#define SCALE 14.426950408889634f
#define E10   22026.465794806718f   // exp(1/tau) exact diagonal term

// ---------- Kernel 1: row-normalize fp32 -> scaled fp8, emit ||q||^2 -----
__global__ __launch_bounds__(256) void normalize_kernel(
    const float* __restrict__ x, unsigned short* __restrict__ q16,
    float* __restrict__ dsq)
{
    int wave = threadIdx.x >> 6;
    int lane = threadIdx.x & 63;
    int row  = blockIdx.x * 4 + wave;
    const float2* xr = (const float2*)(x + (size_t)row * DDIM);
    float2 v = xr[lane];
    float ss = v.x * v.x + v.y * v.y;
    #pragma unroll
    for (int off = 1; off < 64; off <<= 1)
        ss += __shfl_xor(ss, off, 64);
    float rn = sqrtf(SCALE / ss);
    int pk = __builtin_amdgcn_cvt_pk_fp8_f32(v.x * rn, v.y * rn, 0, false);
    q16[(size_t)row * 64 + lane] = (unsigned short)(pk & 0xffff);
    // exact quantized self-energy (matches what the MFMA diagonal computes)
    float d0 = __builtin_amdgcn_cvt_f32_fp8(pk, 0);
    float d1 = __builtin_amdgcn_cvt_f32_fp8(pk, 1);
    float sq = d0 * d0 + d1 * d1;
    #pragma unroll
    for (int off = 1; off < 64; off <<= 1)
        sq += __shfl_xor(sq, off, 64);
    if (lane == 0) dsq[row] = sq;
}

// ---------- Kernel 2: fused fp8 QQ^T + exp2 + masked row-sums ------------
// R6-proven structure: grid = 64 row-blocks x 16 col-chunks, 4 waves/block,
// 128 rows x 512 cols per block, B staged in LDS in 64-col double-buffered
// groups (barriered 2-phase, compiler-managed waits, no inline-asm sync).
// Deltas vs R6: (a) afrag/yrow pinned via asm keep-alive -> compiler cannot
// rematerialize their global loads inside the hot loop (the R1/R5/R10
// pathology); (b) __launch_bounds__(256,6) caps VGPR at 85 -> 6 waves/SIMD
// for +50% latency-hiding TLP.
// Swizzle: logical byte (c,k) at c*128 + (k ^ ((c&7)<<4)) — bits 4-6 only,
// stage granule (16B) untouched (T21-safe); b64 reads conflict-free.
__global__ __launch_bounds__(256, 6) void sim_kernel(
    const unsigned short* __restrict__ q16, const int* __restrict__ y,
    float* __restrict__ topp, float* __restrict__ downp)
{
    __shared__ char smem[2 * GROUP_BYTES];
    __shared__ int  yl[COLS_PER_BLOCK];

    const int bid  = blockIdx.x;
    const int iblk = bid >> 4;
    const int h    = bid & 15;
    const int tid  = threadIdx.x;
    const int lane = tid & 63;
    const int wave = tid >> 6;
    const int lrow = lane & 15;
    const int lhi  = lane >> 4;

    const char* qb = (const char*)q16;
    const int rbase = iblk * ROWS_PER_BLOCK + wave * 32;
    const int jbase = h * COLS_PER_BLOCK;

    yl[tid]       = y[jbase + tid];
    yl[tid + 256] = y[jbase + tid + 256];

    // A fragments: 2 row-tiles x 4 K-slices, 8B each (16 VGPRs total).
    f8x8 afrag[2][4];
    #pragma unroll
    for (int t = 0; t < 2; ++t)
        #pragma unroll
        for (int ks = 0; ks < 4; ++ks)
            afrag[t][ks] = *(const f8x8*)(qb +
                (size_t)(rbase + t * 16 + lrow) * DDIM + ks * 32 + lhi * 8);

    int yrow[2][4];
    #pragma unroll
    for (int t = 0; t < 2; ++t)
        #pragma unroll
        for (int r = 0; r < 4; ++r)
            yrow[t][r] = y[rbase + t * 16 + lhi * 4 + r];

    // Keep-alive pins: force afrag/yrow to be materialized HERE and stay
    // in VGPRs — blocks rematerialization of their loads into the loop.
    #pragma unroll
    for (int t = 0; t < 2; ++t) {
        #pragma unroll
        for (int ks = 0; ks < 4; ++ks)
            asm volatile("" : "+v"(afrag[t][ks]));
        #pragma unroll
        for (int r = 0; r < 4; ++r)
            asm volatile("" : "+v"(yrow[t][r]));
    }

    float top[2][4]  = {{0.f,0.f,0.f,0.f},{0.f,0.f,0.f,0.f}};
    float down[2][4] = {{0.f,0.f,0.f,0.f},{0.f,0.f,0.f,0.f}};

    // stage group g: linear LDS dest, pre-swizzled source (bits 4-6 XOR).
    auto stage = [&](int buf, int g) {
        const int jstart = jbase + g * GROUP_COLS;
        #pragma unroll
        for (int p = 0; p < 2; ++p) {
            int phys = p * 4096 + tid * 16;
            int col  = phys >> 7;
            int L    = phys ^ ((col & 7) << 4);
            const char* src = qb + (size_t)(jstart + col) * DDIM + (L & 127);
            load_lds16(src, smem + buf * GROUP_BYTES + phys);
        }
    };

    stage(0, 0);
    __syncthreads();

    for (int g = 0; g < NGROUPS; ++g) {
        if (g + 1 < NGROUPS) stage((g + 1) & 1, g + 1);

        const char* lbuf = smem + (g & 1) * GROUP_BYTES;

        #pragma unroll
        for (int jt = 0; jt < GROUP_COLS / 16; ++jt) {
            const int cg = jt * 16 + lrow;
            const int ycol = yl[g * GROUP_COLS + cg];
            f8x8 bfrag[4];
            #pragma unroll
            for (int ks = 0; ks < 4; ++ks) {
                int off = cg * DDIM + ((ks * 32 + lhi * 8) ^ ((cg & 7) << 4));
                bfrag[ks] = *(const f8x8*)(lbuf + off);
            }
            #pragma unroll
            for (int t = 0; t < 2; ++t) {
                f32x4 acc = {0.f, 0.f, 0.f, 0.f};
                #pragma unroll
                for (int ks = 0; ks < 4; ++ks)
                    acc = __builtin_amdgcn_mfma_f32_16x16x32_fp8_fp8(
                        afrag[t][ks], bfrag[ks], acc, 0, 0, 0);
                #pragma unroll
                for (int r = 0; r < 4; ++r) {
                    float e = __builtin_amdgcn_exp2f(acc[r]);
                    down[t][r] += e;
                    top[t][r]  += (yrow[t][r] == ycol) ? e : 0.0f;
                }
            }
        }
        __syncthreads();
    }

    #pragma unroll
    for (int m = 1; m < 16; m <<= 1) {
        #pragma unroll
        for (int t = 0; t < 2; ++t)
            #pragma unroll
            for (int r = 0; r < 4; ++r) {
                top[t][r]  += __shfl_xor(top[t][r],  m, 64);
                down[t][r] += __shfl_xor(down[t][r], m, 64);
            }
    }

    if (lrow == 0) {
        #pragma unroll
        for (int t = 0; t < 2; ++t)
            #pragma unroll
            for (int r = 0; r < 4; ++r) {
                int row = rbase + t * 16 + lhi * 4 + r;
                topp [h * NROWS + row] = top[t][r];
                downp[h * NROWS + row] = down[t][r];
            }
    }
}

// ---------- Kernel 3a: per-row loss with exact-diagonal correction -------
__global__ __launch_bounds__(64) void loss_partial_kernel(
    const float* __restrict__ topp, const float* __restrict__ downp,
    const float* __restrict__ dsq, float* __restrict__ partial)
{
    const int lane = threadIdx.x;
    const int r = blockIdx.x * 64 + lane;
    float t = 0.f, d = 0.f;
    #pragma unroll
    for (int hh = 0; hh < NCHUNK; ++hh) {
        t += topp [hh * NROWS + r];
        d += downp[hh * NROWS + r];
    }
    // replace quantized diagonal exp2(||q||^2) with exact e^{1/tau}
    float e2d = __builtin_amdgcn_exp2f(dsq[r]);
    t = t - e2d + E10;
    d = d - e2d + E10;
    float s = __logf(d) - __logf(t);
    #pragma unroll
    for (int off = 1; off < 64; off <<= 1)
        s += __shfl_xor(s, off, 64);
    if (lane == 0) partial[blockIdx.x] = s;
}

// ---------- Kernel 3b: final 128 -> scalar -------------------------------
__global__ __launch_bounds__(64) void loss_final_kernel(
    const float* __restrict__ partial, float* __restrict__ out)
{
    const int lane = threadIdx.x;
    float s = partial[lane] + partial[lane + 64];
    #pragma unroll
    for (int off = 1; off < 64; off <<= 1)
        s += __shfl_xor(s, off, 64);
    if (lane == 0) out[0] = s / (float)NROWS;
}

extern "C" void kernel_launch(void* const* d_in, const int* in_sizes, int n_in,
                              void* d_out, int out_size, void* d_ws, size_t ws_size,
                              hipStream_t stream)
{
    const float* x = (const float*)d_in[0];
    const int*   y = (const int*)d_in[1];
    float* out = (float*)d_out;

    char* ws = (char*)d_ws;
    unsigned short* q16 = (unsigned short*)ws;                     // 1 MB fp8
    float* topp  = (float*)(ws + (size_t)NROWS * DDIM);            // 512 KB
    float* downp = topp + NCHUNK * NROWS;                          // 512 KB
    float* dsq     = downp + NCHUNK * NROWS;                       // 32 KB
    float* partial = dsq + NROWS;                                  // 512 B

    normalize_kernel<<<NROWS / 4, 256, 0, stream>>>(x, q16, dsq);
    sim_kernel<<<64 * NCHUNK, 256, 0, stream>>>(q16, y, topp, downp);
    loss_partial_kernel<<<NROWS / 64, 64, 0, stream>>>(topp, downp, dsq, partial);
    loss_final_kernel<<<1, 64, 0, stream>>>(partial, out);
}

// Round 12
// 43.599 us; speedup vs baseline: 1.4229x; 1.1966x over previous
//
#include <hip/hip_runtime.h>
#include <hip/hip_bf16.h>
#include <stdint.h>

#define NROWS 8192
#define DDIM  128
#define NBLK  64                        // 8192 / 128
#define NPAIR (NBLK * (NBLK + 1) / 2)   // 2080 upper-triangle tile pairs
#define BI 128
#define BJ 128
#define PANEL_BYTES (BJ * DDIM)         // fp8: 16384 B

typedef __attribute__((ext_vector_type(4))) float f32x4;
typedef long f8x8;           // 8 fp8 elements = 8 bytes = 2 VGPRs

__device__ __forceinline__ void load_lds16(const void* g, void* l) {
    __builtin_amdgcn_global_load_lds(
        (const __attribute__((address_space(1))) void*)g,
        (__attribute__((address_space(3))) void*)l, 16, 0, 0);
}

// (1/tau) * log2(e); q is pre-scaled by sqrt of this so exp2(acc) = e^{s/tau}.
#define SCALE 14.426950408889634f
#define E10   22026.465794806718f   // exp(1/tau) exact diagonal term

// ---------- Kernel 1: row-normalize fp32 -> scaled fp8, emit ||q||^2 -----
__global__ __launch_bounds__(256) void normalize_kernel(
    const float* __restrict__ x, unsigned short* __restrict__ q16,
    float* __restrict__ dsq)
{
    int wave = threadIdx.x >> 6;
    int lane = threadIdx.x & 63;
    int row  = blockIdx.x * 4 + wave;
    const float2* xr = (const float2*)(x + (size_t)row * DDIM);
    float2 v = xr[lane];
    float ss = v.x * v.x + v.y * v.y;
    #pragma unroll
    for (int off = 1; off < 64; off <<= 1)
        ss += __shfl_xor(ss, off, 64);
    float rn = sqrtf(SCALE / ss);
    int pk = __builtin_amdgcn_cvt_pk_fp8_f32(v.x * rn, v.y * rn, 0, false);
    q16[(size_t)row * 64 + lane] = (unsigned short)(pk & 0xffff);
    // exact quantized self-energy (matches what the MFMA diagonal computes)
    float d0 = __builtin_amdgcn_cvt_f32_fp8(pk, 0);
    float d1 = __builtin_amdgcn_cvt_f32_fp8(pk, 1);
    float sq = d0 * d0 + d1 * d1;
    #pragma unroll
    for (int off = 1; off < 64; off <<= 1)
        sq += __shfl_xor(sq, off, 64);
    if (lane == 0) dsq[row] = sq;
}

// ---------- Kernel 2: SYMMETRIC fused fp8 QQ^T + exp2 + masked sums ------
// Upper-triangle tile pairs (ib <= jb), 2080 blocks of 128x128. Each e_ij
// credits row i (row-sum, regs) and row j (col-sum). Col-sums use only 8
// registers: accumulate per quad of j-tiles, fold across lhi (2 shfls),
// write-once into wave-private LDS scol[wave][col]; cross-wave fold after
// one barrier. Unique-writer slots (R10-proven): row-side -> slot jb,
// col-side -> slot ib; diagonal skips col-side. No atomics, deterministic.
// Staging (R6-proven): whole 16 KB j-panel once via pre-swizzled source
// (XOR on byte bits 4-6 keyed by col&7), one barrier, barrier-free loop.
// afrag/yrow pinned to block the R1/R5/R10/R11 remat/spill pathology.
__global__ __launch_bounds__(256, 4) void sim_kernel(
    const unsigned short* __restrict__ q16, const int* __restrict__ y,
    float* __restrict__ topp, float* __restrict__ downp)
{
    __shared__ char  smem[PANEL_BYTES];
    __shared__ int   yl[BJ];
    __shared__ float scolD[4][BJ];
    __shared__ float scolT[4][BJ];

    // decode upper-triangle pair: 0 <= ib <= jb < 64
    int k = blockIdx.x;
    int jb = (int)((sqrtf(8.0f * (float)k + 1.0f) - 1.0f) * 0.5f);
    while ((jb + 1) * (jb + 2) / 2 <= k) ++jb;
    while (jb * (jb + 1) / 2 > k) --jb;
    int ib = k - jb * (jb + 1) / 2;

    const int tid  = threadIdx.x;
    const int lane = tid & 63;
    const int wave = tid >> 6;
    const int lrow = lane & 15;
    const int lhi  = lane >> 4;

    const char* qb = (const char*)q16;
    const int rbase = ib * BI + wave * 32;
    const int jbase = jb * BJ;

    if (tid < BJ) yl[tid] = y[jbase + tid];

    // stage the whole j-panel: linear LDS dest, pre-swizzled source
    #pragma unroll
    for (int p = 0; p < 4; ++p) {
        int phys = p * 4096 + tid * 16;
        int col  = phys >> 7;
        int L    = phys ^ ((col & 7) << 4);
        load_lds16(qb + (size_t)(jbase + col) * DDIM + (L & 127), smem + phys);
    }

    // A fragments: 2 row-tiles x 4 K-slices, 8B each (16 VGPRs total).
    f8x8 afrag[2][4];
    #pragma unroll
    for (int t = 0; t < 2; ++t)
        #pragma unroll
        for (int ks = 0; ks < 4; ++ks)
            afrag[t][ks] = *(const f8x8*)(qb +
                (size_t)(rbase + t * 16 + lrow) * DDIM + ks * 32 + lhi * 8);

    int yrow[2][4];
    #pragma unroll
    for (int t = 0; t < 2; ++t)
        #pragma unroll
        for (int r = 0; r < 4; ++r)
            yrow[t][r] = y[rbase + t * 16 + lhi * 4 + r];

    // Keep-alive pins: force afrag/yrow to stay materialized in VGPRs.
    #pragma unroll
    for (int t = 0; t < 2; ++t) {
        #pragma unroll
        for (int ks = 0; ks < 4; ++ks)
            asm volatile("" : "+v"(afrag[t][ks]));
        #pragma unroll
        for (int r = 0; r < 4; ++r)
            asm volatile("" : "+v"(yrow[t][r]));
    }

    __syncthreads();   // panel + labels staged; hot loop is barrier-free

    float top[2][4]  = {};
    float down[2][4] = {};
    float colD[4] = {0.f, 0.f, 0.f, 0.f};
    float colT[4] = {0.f, 0.f, 0.f, 0.f};

    #pragma unroll
    for (int jt = 0; jt < 8; ++jt) {
        const int cg = jt * 16 + lrow;
        const int ycol = yl[cg];
        f8x8 bfrag[4];
        #pragma unroll
        for (int ks = 0; ks < 4; ++ks) {
            int off = cg * DDIM + ((ks * 32 + lhi * 8) ^ ((cg & 7) << 4));
            bfrag[ks] = *(const f8x8*)(smem + off);
        }
        #pragma unroll
        for (int t = 0; t < 2; ++t) {
            f32x4 acc = {0.f, 0.f, 0.f, 0.f};
            #pragma unroll
            for (int ks = 0; ks < 4; ++ks)
                acc = __builtin_amdgcn_mfma_f32_16x16x32_fp8_fp8(
                    afrag[t][ks], bfrag[ks], acc, 0, 0, 0);
            #pragma unroll
            for (int r = 0; r < 4; ++r) {
                float e  = __builtin_amdgcn_exp2f(acc[r]);
                float me = (yrow[t][r] == ycol) ? e : 0.0f;
                down[t][r] += e;
                top[t][r]  += me;
                colD[jt & 3] += e;    // column partial (8 rows per lane)
                colT[jt & 3] += me;
            }
        }
        // fold col-partials after each quad: 2 shfls -> full 32-row sums,
        // write-once into wave-private LDS row (no RMW, no atomics).
        if (jt == 3 || jt == 7) {
            const int quad = jt >> 2;
            #pragma unroll
            for (int q = 0; q < 4; ++q) {
                float vD = colD[q], vT = colT[q];
                vD += __shfl_xor(vD, 16, 64);
                vD += __shfl_xor(vD, 32, 64);
                vT += __shfl_xor(vT, 16, 64);
                vT += __shfl_xor(vT, 32, 64);
                if (lane < 16) {
                    scolD[wave][(quad * 4 + q) * 16 + lane] = vD;
                    scolT[wave][(quad * 4 + q) * 16 + lane] = vT;
                }
                colD[q] = 0.f;
                colT[q] = 0.f;
            }
        }
    }

    // ---- row-side: reduce across the 16 column-lanes ----
    #pragma unroll
    for (int m = 1; m < 16; m <<= 1) {
        #pragma unroll
        for (int t = 0; t < 2; ++t)
            #pragma unroll
            for (int r = 0; r < 4; ++r) {
                top[t][r]  += __shfl_xor(top[t][r],  m, 64);
                down[t][r] += __shfl_xor(down[t][r], m, 64);
            }
    }
    if (lrow == 0) {
        #pragma unroll
        for (int t = 0; t < 2; ++t)
            #pragma unroll
            for (int r = 0; r < 4; ++r) {
                int row = rbase + t * 16 + lhi * 4 + r;
                topp [jb * NROWS + row] = top[t][r];
                downp[jb * NROWS + row] = down[t][r];
            }
    }

    // ---- col-side: cross-wave fold + write (skip on diagonal) ----
    __syncthreads();
    if (ib != jb && tid < BJ) {
        float cd = scolD[0][tid] + scolD[1][tid] + scolD[2][tid] + scolD[3][tid];
        float ct = scolT[0][tid] + scolT[1][tid] + scolT[2][tid] + scolT[3][tid];
        downp[ib * NROWS + jbase + tid] = cd;
        topp [ib * NROWS + jbase + tid] = ct;
    }
}

// ---------- Kernel 3a: per-row loss with exact-diagonal correction -------
__global__ __launch_bounds__(64) void loss_partial_kernel(
    const float* __restrict__ topp, const float* __restrict__ downp,
    const float* __restrict__ dsq, float* __restrict__ partial)
{
    const int lane = threadIdx.x;
    const int r = blockIdx.x * 64 + lane;
    float t = 0.f, d = 0.f;
    #pragma unroll 8
    for (int hh = 0; hh < NBLK; ++hh) {
        t += topp [hh * NROWS + r];
        d += downp[hh * NROWS + r];
    }
    // replace quantized diagonal exp2(||q||^2) with exact e^{1/tau}
    float e2d = __builtin_amdgcn_exp2f(dsq[r]);
    t = t - e2d + E10;
    d = d - e2d + E10;
    float s = __logf(d) - __logf(t);
    #pragma unroll
    for (int off = 1; off < 64; off <<= 1)
        s += __shfl_xor(s, off, 64);
    if (lane == 0) partial[blockIdx.x] = s;
}

// ---------- Kernel 3b: final 128 -> scalar -------------------------------
__global__ __launch_bounds__(64) void loss_final_kernel(
    const float* __restrict__ partial, float* __restrict__ out)
{
    const int lane = threadIdx.x;
    float s = partial[lane] + partial[lane + 64];
    #pragma unroll
    for (int off = 1; off < 64; off <<= 1)
        s += __shfl_xor(s, off, 64);
    if (lane == 0) out[0] = s / (float)NROWS;
}

extern "C" void kernel_launch(void* const* d_in, const int* in_sizes, int n_in,
                              void* d_out, int out_size, void* d_ws, size_t ws_size,
                              hipStream_t stream)
{
    const float* x = (const float*)d_in[0];
    const int*   y = (const int*)d_in[1];
    float* out = (float*)d_out;

    char* ws = (char*)d_ws;
    unsigned short* q16 = (unsigned short*)ws;                     // 1 MB fp8
    float* topp  = (float*)(ws + (size_t)NROWS * DDIM);            // 2 MB
    float* downp = topp + NBLK * NROWS;                            // 2 MB
    float* dsq     = downp + NBLK * NROWS;                         // 32 KB
    float* partial = dsq + NROWS;                                  // 512 B

    normalize_kernel<<<NROWS / 4, 256, 0, stream>>>(x, q16, dsq);
    sim_kernel<<<NPAIR, 256, 0, stream>>>(q16, y, topp, downp);
    loss_partial_kernel<<<NROWS / 64, 64, 0, stream>>>(topp, downp, dsq, partial);
    loss_final_kernel<<<1, 64, 0, stream>>>(partial, out);
}

// Round 13
// 40.846 us; speedup vs baseline: 1.5188x; 1.0674x over previous
//
#include <hip/hip_runtime.h>
#include <hip/hip_bf16.h>
#include <stdint.h>

#define NROWS 8192
#define DDIM  128
#define NBLK  64                        // 8192 / 128
#define NPAIR (NBLK * (NBLK + 1) / 2)   // 2080 upper-triangle tile pairs
#define BI 128
#define BJ 128
#define PANEL_BYTES (BJ * DDIM)         // fp8: 16384 B

typedef __attribute__((ext_vector_type(4))) float f32x4;
typedef long f8x8;           // 8 fp8 elements = 8 bytes = 2 VGPRs

__device__ __forceinline__ void load_lds16(const void* g, void* l) {
    __builtin_amdgcn_global_load_lds(
        (const __attribute__((address_space(1))) void*)g,
        (__attribute__((address_space(3))) void*)l, 16, 0, 0);
}

// (1/tau) * log2(e); q is pre-scaled by sqrt of this so exp2(acc) = e^{s/tau}.
#define SCALE 14.426950408889634f
#define E10   22026.465794806718f   // exp(1/tau) exact diagonal term

// ---------- Kernel 1: row-normalize fp32 -> scaled fp8, emit ||q||^2 -----
__global__ __launch_bounds__(256) void normalize_kernel(
    const float* __restrict__ x, unsigned short* __restrict__ q16,
    float* __restrict__ dsq)
{
    int wave = threadIdx.x >> 6;
    int lane = threadIdx.x & 63;
    int row  = blockIdx.x * 4 + wave;
    const float2* xr = (const float2*)(x + (size_t)row * DDIM);
    float2 v = xr[lane];
    float ss = v.x * v.x + v.y * v.y;
    #pragma unroll
    for (int off = 1; off < 64; off <<= 1)
        ss += __shfl_xor(ss, off, 64);
    float rn = sqrtf(SCALE / ss);
    int pk = __builtin_amdgcn_cvt_pk_fp8_f32(v.x * rn, v.y * rn, 0, false);
    q16[(size_t)row * 64 + lane] = (unsigned short)(pk & 0xffff);
    // exact quantized self-energy (matches what the MFMA diagonal computes)
    float d0 = __builtin_amdgcn_cvt_f32_fp8(pk, 0);
    float d1 = __builtin_amdgcn_cvt_f32_fp8(pk, 1);
    float sq = d0 * d0 + d1 * d1;
    #pragma unroll
    for (int off = 1; off < 64; off <<= 1)
        sq += __shfl_xor(sq, off, 64);
    if (lane == 0) dsq[row] = sq;
}

// ---------- Kernel 2: SYMMETRIC fused fp8 QQ^T + exp2 + masked sums ------
// UNCHANGED from round 12 (passed). Upper-triangle tile pairs (ib <= jb),
// 2080 blocks of 128x128; row-side -> slot jb, col-side -> slot ib;
// diagonal skips col-side; unique writer per (slot,rowblock); no atomics.
__global__ __launch_bounds__(256, 4) void sim_kernel(
    const unsigned short* __restrict__ q16, const int* __restrict__ y,
    float* __restrict__ topp, float* __restrict__ downp)
{
    __shared__ char  smem[PANEL_BYTES];
    __shared__ int   yl[BJ];
    __shared__ float scolD[4][BJ];
    __shared__ float scolT[4][BJ];

    // decode upper-triangle pair: 0 <= ib <= jb < 64
    int k = blockIdx.x;
    int jb = (int)((sqrtf(8.0f * (float)k + 1.0f) - 1.0f) * 0.5f);
    while ((jb + 1) * (jb + 2) / 2 <= k) ++jb;
    while (jb * (jb + 1) / 2 > k) --jb;
    int ib = k - jb * (jb + 1) / 2;

    const int tid  = threadIdx.x;
    const int lane = tid & 63;
    const int wave = tid >> 6;
    const int lrow = lane & 15;
    const int lhi  = lane >> 4;

    const char* qb = (const char*)q16;
    const int rbase = ib * BI + wave * 32;
    const int jbase = jb * BJ;

    if (tid < BJ) yl[tid] = y[jbase + tid];

    // stage the whole j-panel: linear LDS dest, pre-swizzled source
    #pragma unroll
    for (int p = 0; p < 4; ++p) {
        int phys = p * 4096 + tid * 16;
        int col  = phys >> 7;
        int L    = phys ^ ((col & 7) << 4);
        load_lds16(qb + (size_t)(jbase + col) * DDIM + (L & 127), smem + phys);
    }

    // A fragments: 2 row-tiles x 4 K-slices, 8B each (16 VGPRs total).
    f8x8 afrag[2][4];
    #pragma unroll
    for (int t = 0; t < 2; ++t)
        #pragma unroll
        for (int ks = 0; ks < 4; ++ks)
            afrag[t][ks] = *(const f8x8*)(qb +
                (size_t)(rbase + t * 16 + lrow) * DDIM + ks * 32 + lhi * 8);

    int yrow[2][4];
    #pragma unroll
    for (int t = 0; t < 2; ++t)
        #pragma unroll
        for (int r = 0; r < 4; ++r)
            yrow[t][r] = y[rbase + t * 16 + lhi * 4 + r];

    // Keep-alive pins: force afrag/yrow to stay materialized in VGPRs.
    #pragma unroll
    for (int t = 0; t < 2; ++t) {
        #pragma unroll
        for (int ks = 0; ks < 4; ++ks)
            asm volatile("" : "+v"(afrag[t][ks]));
        #pragma unroll
        for (int r = 0; r < 4; ++r)
            asm volatile("" : "+v"(yrow[t][r]));
    }

    __syncthreads();   // panel + labels staged; hot loop is barrier-free

    float top[2][4]  = {};
    float down[2][4] = {};
    float colD[4] = {0.f, 0.f, 0.f, 0.f};
    float colT[4] = {0.f, 0.f, 0.f, 0.f};

    #pragma unroll
    for (int jt = 0; jt < 8; ++jt) {
        const int cg = jt * 16 + lrow;
        const int ycol = yl[cg];
        f8x8 bfrag[4];
        #pragma unroll
        for (int ks = 0; ks < 4; ++ks) {
            int off = cg * DDIM + ((ks * 32 + lhi * 8) ^ ((cg & 7) << 4));
            bfrag[ks] = *(const f8x8*)(smem + off);
        }
        #pragma unroll
        for (int t = 0; t < 2; ++t) {
            f32x4 acc = {0.f, 0.f, 0.f, 0.f};
            #pragma unroll
            for (int ks = 0; ks < 4; ++ks)
                acc = __builtin_amdgcn_mfma_f32_16x16x32_fp8_fp8(
                    afrag[t][ks], bfrag[ks], acc, 0, 0, 0);
            #pragma unroll
            for (int r = 0; r < 4; ++r) {
                float e  = __builtin_amdgcn_exp2f(acc[r]);
                float me = (yrow[t][r] == ycol) ? e : 0.0f;
                down[t][r] += e;
                top[t][r]  += me;
                colD[jt & 3] += e;    // column partial (8 rows per lane)
                colT[jt & 3] += me;
            }
        }
        // fold col-partials after each quad: 2 shfls -> full 32-row sums,
        // write-once into wave-private LDS row (no RMW, no atomics).
        if (jt == 3 || jt == 7) {
            const int quad = jt >> 2;
            #pragma unroll
            for (int q = 0; q < 4; ++q) {
                float vD = colD[q], vT = colT[q];
                vD += __shfl_xor(vD, 16, 64);
                vD += __shfl_xor(vD, 32, 64);
                vT += __shfl_xor(vT, 16, 64);
                vT += __shfl_xor(vT, 32, 64);
                if (lane < 16) {
                    scolD[wave][(quad * 4 + q) * 16 + lane] = vD;
                    scolT[wave][(quad * 4 + q) * 16 + lane] = vT;
                }
                colD[q] = 0.f;
                colT[q] = 0.f;
            }
        }
    }

    // ---- row-side: reduce across the 16 column-lanes ----
    #pragma unroll
    for (int m = 1; m < 16; m <<= 1) {
        #pragma unroll
        for (int t = 0; t < 2; ++t)
            #pragma unroll
            for (int r = 0; r < 4; ++r) {
                top[t][r]  += __shfl_xor(top[t][r],  m, 64);
                down[t][r] += __shfl_xor(down[t][r], m, 64);
            }
    }
    if (lrow == 0) {
        #pragma unroll
        for (int t = 0; t < 2; ++t)
            #pragma unroll
            for (int r = 0; r < 4; ++r) {
                int row = rbase + t * 16 + lhi * 4 + r;
                topp [jb * NROWS + row] = top[t][r];
                downp[jb * NROWS + row] = down[t][r];
            }
    }

    // ---- col-side: cross-wave fold + write (skip on diagonal) ----
    __syncthreads();
    if (ib != jb && tid < BJ) {
        float cd = scolD[0][tid] + scolD[1][tid] + scolD[2][tid] + scolD[3][tid];
        float ct = scolT[0][tid] + scolT[1][tid] + scolT[2][tid] + scolT[3][tid];
        downp[ib * NROWS + jbase + tid] = cd;
        topp [ib * NROWS + jbase + tid] = ct;
    }
}

// ---------- Kernel 3a: slot-reduce + per-row loss, occupancy-fixed -------
// 128 blocks x 256 threads (512 waves chip-wide). Thread (r, part): r =
// b*64 + (tid&63), part = tid>>6 sums 16 of the 64 slots (32 independent
// coalesced loads, fully unrolled); 4-part fold via LDS; wave 0 applies the
// exact-diagonal correction and computes log(d)-log(t), wave-reduces, one
// partial per block.
__global__ __launch_bounds__(256) void loss_partial_kernel(
    const float* __restrict__ topp, const float* __restrict__ downp,
    const float* __restrict__ dsq, float* __restrict__ partial)
{
    __shared__ float sT[4][64];
    __shared__ float sD[4][64];

    const int tid  = threadIdx.x;
    const int lane = tid & 63;
    const int part = tid >> 6;
    const int r    = blockIdx.x * 64 + lane;

    float t = 0.f, d = 0.f;
    #pragma unroll
    for (int i = 0; i < 16; ++i) {
        int hh = part * 16 + i;
        t += topp [hh * NROWS + r];
        d += downp[hh * NROWS + r];
    }
    sT[part][lane] = t;
    sD[part][lane] = d;
    __syncthreads();

    if (part == 0) {
        t = sT[0][lane] + sT[1][lane] + sT[2][lane] + sT[3][lane];
        d = sD[0][lane] + sD[1][lane] + sD[2][lane] + sD[3][lane];
        // replace quantized diagonal exp2(||q||^2) with exact e^{1/tau}
        float e2d = __builtin_amdgcn_exp2f(dsq[r]);
        t = t - e2d + E10;
        d = d - e2d + E10;
        float s = __logf(d) - __logf(t);
        #pragma unroll
        for (int off = 1; off < 64; off <<= 1)
            s += __shfl_xor(s, off, 64);
        if (lane == 0) partial[blockIdx.x] = s;
    }
}

// ---------- Kernel 3b: final 128 -> scalar -------------------------------
__global__ __launch_bounds__(64) void loss_final_kernel(
    const float* __restrict__ partial, float* __restrict__ out)
{
    const int lane = threadIdx.x;
    float s = partial[lane] + partial[lane + 64];
    #pragma unroll
    for (int off = 1; off < 64; off <<= 1)
        s += __shfl_xor(s, off, 64);
    if (lane == 0) out[0] = s / (float)NROWS;
}

extern "C" void kernel_launch(void* const* d_in, const int* in_sizes, int n_in,
                              void* d_out, int out_size, void* d_ws, size_t ws_size,
                              hipStream_t stream)
{
    const float* x = (const float*)d_in[0];
    const int*   y = (const int*)d_in[1];
    float* out = (float*)d_out;

    char* ws = (char*)d_ws;
    unsigned short* q16 = (unsigned short*)ws;                     // 1 MB fp8
    float* topp  = (float*)(ws + (size_t)NROWS * DDIM);            // 2 MB
    float* downp = topp + NBLK * NROWS;                            // 2 MB
    float* dsq     = downp + NBLK * NROWS;                         // 32 KB
    float* partial = dsq + NROWS;                                  // 512 B

    normalize_kernel<<<NROWS / 4, 256, 0, stream>>>(x, q16, dsq);
    sim_kernel<<<NPAIR, 256, 0, stream>>>(q16, y, topp, downp);
    loss_partial_kernel<<<NROWS / 64, 256, 0, stream>>>(topp, downp, dsq, partial);
    loss_final_kernel<<<1, 64, 0, stream>>>(partial, out);
}